// Round 1
// baseline (123.166 us; speedup 1.0000x reference)
//
#include <hip/hip_runtime.h>

// Problem constants (from reference)
constexpr int S = 8192;    // source codes
constexpr int G = 1024;    // groups
constexpr int T = 4096;    // time segments (t0 sorted ascending!)
constexpr int E = 16384;   // events
constexpr int CH = 32;     // chunk length along T for two-level scan
constexpr int NC = T / CH; // 128 chunks
constexpr int G4 = G / 4;  // 256 float4-columns per row

// K1: zero the diff/output array (harness poisons d_out with 0xAA)
__global__ __launch_bounds__(256) void k_zero(float4* __restrict__ p, int n4) {
    int i = blockIdx.x * blockDim.x + threadIdx.x;
    if (i < n4) p[i] = make_float4(0.f, 0.f, 0.f, 0.f);
}

// K2: per-event difference-array scatter.
// Active t-range is [lo, hi): lo = lower_bound(t0, start), hi = lower_bound(t0, end)
// because mask = (start <= t0) & (t0 < end) and t0 is sorted.
__global__ __launch_bounds__(256) void k_scatter(
        const int* __restrict__ index, const float* __restrict__ rate,
        const float* __restrict__ start, const float* __restrict__ endt,
        const float* __restrict__ t0, const int* __restrict__ gid,
        const float* __restrict__ wts, float* __restrict__ diff) {
    int e = blockIdx.x * blockDim.x + threadIdx.x;
    if (e >= E) return;
    float s = start[e], en = endt[e];
    // lower_bound for start
    int lo = 0, hi = T;
    while (lo < hi) { int m = (lo + hi) >> 1; if (t0[m] < s) lo = m + 1; else hi = m; }
    // lower_bound for end (end >= start, so search [lo, T))
    int lo2 = lo, hi2 = T;
    while (lo2 < hi2) { int m = (lo2 + hi2) >> 1; if (t0[m] < en) lo2 = m + 1; else hi2 = m; }
    if (lo < lo2) {
        int ix = index[e];
        float w = rate[e] * wts[ix];
        int g = gid[ix];
        atomicAdd(diff + (size_t)lo * G + g, w);
        if (lo2 < T) atomicAdd(diff + (size_t)lo2 * G + g, -w);
    }
}

// K3: per-(chunk, float4-column) partial sums of the diff array.
// block = 256 threads = one chunk's 256 float4 columns; fully coalesced.
__global__ __launch_bounds__(256) void k_chunksum(const float4* __restrict__ diff,
                                                  float4* __restrict__ s1) {
    int c = blockIdx.x;
    int g4 = threadIdx.x;
    const float4* p = diff + (size_t)c * CH * G4 + g4;
    float4 a = make_float4(0.f, 0.f, 0.f, 0.f);
    #pragma unroll 8
    for (int t = 0; t < CH; ++t) {
        float4 v = p[(size_t)t * G4];
        a.x += v.x; a.y += v.y; a.z += v.z; a.w += v.w;
    }
    s1[c * G4 + g4] = a;
}

// K4: in-place column prefix-sum. Each thread: exclusive prefix of its chunk
// from the (L2-resident, 512 KB) partials, then running sum over its 32 rows.
// Read-then-write at the same address by the same thread -> in-place safe.
__global__ __launch_bounds__(256) void k_scan(float4* __restrict__ out,
                                              const float4* __restrict__ s1) {
    int c = blockIdx.x;
    int g4 = threadIdx.x;
    float4 r = make_float4(0.f, 0.f, 0.f, 0.f);
    for (int cc = 0; cc < c; ++cc) {
        float4 v = s1[cc * G4 + g4];
        r.x += v.x; r.y += v.y; r.z += v.z; r.w += v.w;
    }
    float4* p = out + (size_t)c * CH * G4 + g4;
    #pragma unroll 4
    for (int t = 0; t < CH; ++t) {
        float4 v = p[(size_t)t * G4];
        r.x += v.x; r.y += v.y; r.z += v.z; r.w += v.w;
        p[(size_t)t * G4] = r;
    }
}

extern "C" void kernel_launch(void* const* d_in, const int* in_sizes, int n_in,
                              void* d_out, int out_size, void* d_ws, size_t ws_size,
                              hipStream_t stream) {
    const int*   index = (const int*)  d_in[0];
    const float* rate  = (const float*)d_in[1];
    const float* start = (const float*)d_in[2];
    const float* endt  = (const float*)d_in[3];
    const float* t0    = (const float*)d_in[4];
    const int*   gid   = (const int*)  d_in[5];
    const float* wts   = (const float*)d_in[6];
    float* out = (float*)d_out;           // doubles as the diff array (16 MB)
    float4* s1 = (float4*)d_ws;           // NC*G4 float4 = 512 KB chunk partials

    int n4 = T * G / 4;
    k_zero<<<(n4 + 255) / 256, 256, 0, stream>>>((float4*)out, n4);
    k_scatter<<<E / 256, 256, 0, stream>>>(index, rate, start, endt, t0, gid, wts, out);
    k_chunksum<<<NC, 256, 0, stream>>>((const float4*)out, s1);
    k_scan<<<NC, 256, 0, stream>>>((float4*)out, (const float4*)s1);
}

// Round 2
// 101.665 us; speedup vs baseline: 1.2115x; 1.2115x over previous
//
#include <hip/hip_runtime.h>

// Problem constants (from reference)
constexpr int S = 8192;    // source codes
constexpr int G = 1024;    // groups
constexpr int T = 4096;    // time segments (t0 sorted ascending)
constexpr int E = 16384;   // events
constexpr int CH = 16;     // output rows per block
constexpr int NC = T / CH; // 256 blocks -> 1 per CU

// K1: per-event prep. Two binary searches over sorted t0 give the contiguous
// active t-range [lo, hi); pack (lo, hi, g, w) into one int4 record.
__global__ __launch_bounds__(256) void k_prep(
        const int* __restrict__ index, const float* __restrict__ rate,
        const float* __restrict__ start, const float* __restrict__ endt,
        const float* __restrict__ t0, const int* __restrict__ gid,
        const float* __restrict__ wts, int4* __restrict__ rec) {
    int e = blockIdx.x * blockDim.x + threadIdx.x;
    if (e >= E) return;
    float s = start[e], en = endt[e];
    int lo = 0, hi = T;                      // lower_bound(t0, s)
    while (lo < hi) { int m = (lo + hi) >> 1; if (t0[m] < s) lo = m + 1; else hi = m; }
    int lo2 = lo, hi2 = T;                   // lower_bound(t0, en), en >= s
    while (lo2 < hi2) { int m = (lo2 + hi2) >> 1; if (t0[m] < en) lo2 = m + 1; else hi2 = m; }
    int ix = index[e];
    float w = rate[e] * wts[ix];
    int4 r; r.x = lo; r.y = lo2; r.z = gid[ix]; r.w = __float_as_int(w);
    rec[e] = r;
}

// K2: one block per CH-row slab of out. Slab diff array in LDS; every block
// streams all E records (coalesced 16B loads, L2-resident), clamps the event
// interval to its slab, does <=2 LDS atomics, then scans columns and writes
// the slab with coalesced float4 stores. No global diff array, no zeroing of
// d_out needed (every element is overwritten).
__global__ __launch_bounds__(256) void k_main(const int4* __restrict__ rec,
                                              float* __restrict__ out) {
    __shared__ float diff[CH * G];           // 16*1024*4 = 64 KB
    int tid = threadIdx.x;
    int tb = blockIdx.x * CH;                // first t-row of this slab

    float4* d4 = (float4*)diff;
    #pragma unroll
    for (int i = tid; i < CH * G / 4; i += 256)
        d4[i] = make_float4(0.f, 0.f, 0.f, 0.f);
    __syncthreads();

    for (int e = tid; e < E; e += 256) {
        int4 r = rec[e];
        int lo = max(r.x - tb, 0);
        int hi = min(r.y - tb, CH);
        if (lo >= hi) continue;              // no overlap with this slab
        float w = __int_as_float(r.w);
        atomicAdd(diff + lo * G + r.z, w);
        if (hi < CH) atomicAdd(diff + hi * G + r.z, -w);
    }
    __syncthreads();

    // Column prefix-sum: g = tid + 256*c -> consecutive lanes hit consecutive
    // banks (conflict-free); 4 independent 16-long chains per thread.
    #pragma unroll
    for (int c = 0; c < 4; ++c) {
        int g = tid + 256 * c;
        float rsum = 0.f;
        #pragma unroll
        for (int t = 0; t < CH; ++t) {
            rsum += diff[t * G + g];
            diff[t * G + g] = rsum;
        }
    }
    __syncthreads();

    float4* o4 = (float4*)(out + (size_t)tb * G);
    #pragma unroll
    for (int i = tid; i < CH * G / 4; i += 256)
        o4[i] = d4[i];
}

extern "C" void kernel_launch(void* const* d_in, const int* in_sizes, int n_in,
                              void* d_out, int out_size, void* d_ws, size_t ws_size,
                              hipStream_t stream) {
    const int*   index = (const int*)  d_in[0];
    const float* rate  = (const float*)d_in[1];
    const float* start = (const float*)d_in[2];
    const float* endt  = (const float*)d_in[3];
    const float* t0    = (const float*)d_in[4];
    const int*   gid   = (const int*)  d_in[5];
    const float* wts   = (const float*)d_in[6];
    float* out = (float*)d_out;
    int4* rec = (int4*)d_ws;                 // E * 16 B = 256 KB

    k_prep<<<(E + 255) / 256, 256, 0, stream>>>(index, rate, start, endt, t0, gid, wts, rec);
    k_main<<<NC, 256, 0, stream>>>(rec, out);
}

// Round 3
// 88.715 us; speedup vs baseline: 1.3883x; 1.1460x over previous
//
#include <hip/hip_runtime.h>

// Problem constants (from reference)
constexpr int S = 8192;    // source codes
constexpr int G = 1024;    // groups
constexpr int T = 4096;    // time segments (t0 sorted ascending)
constexpr int E = 16384;   // events
constexpr int CH = 16;     // output rows per block
constexpr int NC = T / CH; // 256 blocks -> 1 per CU
constexpr int BT = 1024;   // k_main block threads (16 waves -> 4 waves/SIMD)

// K1: per-event prep. Two binary searches over sorted t0 give the contiguous
// active t-range [lo, hi); pack (lo, hi, g, w) into one int4 record.
__global__ __launch_bounds__(256) void k_prep(
        const int* __restrict__ index, const float* __restrict__ rate,
        const float* __restrict__ start, const float* __restrict__ endt,
        const float* __restrict__ t0, const int* __restrict__ gid,
        const float* __restrict__ wts, int4* __restrict__ rec) {
    int e = blockIdx.x * blockDim.x + threadIdx.x;
    if (e >= E) return;
    float s = start[e], en = endt[e];
    int lo = 0, hi = T;                      // lower_bound(t0, s)
    while (lo < hi) { int m = (lo + hi) >> 1; if (t0[m] < s) lo = m + 1; else hi = m; }
    int lo2 = lo, hi2 = T;                   // lower_bound(t0, en), en >= s
    while (lo2 < hi2) { int m = (lo2 + hi2) >> 1; if (t0[m] < en) lo2 = m + 1; else hi2 = m; }
    int ix = index[e];
    float w = rate[e] * wts[ix];
    int4 r; r.x = lo; r.y = lo2; r.z = gid[ix]; r.w = __float_as_int(w);
    rec[e] = r;
}

// K2: one 1024-thread block per CH-row slab of out (16 waves/CU -> latency
// hiding). Slab diff array in LDS; the block streams all E records
// (coalesced 16B loads, L2-resident), clamps each event interval to its
// slab, does <=2 LDS atomics, then one conflict-free column scan (one
// g-column per thread) and a coalesced float4 slab write. Every output
// element is overwritten, so no global zeroing pass is needed.
__global__ __launch_bounds__(BT) void k_main(const int4* __restrict__ rec,
                                             float* __restrict__ out) {
    __shared__ float diff[CH * G];           // 16*1024*4 = 64 KB
    int tid = threadIdx.x;
    int tb = blockIdx.x * CH;                // first t-row of this slab

    float4* d4 = (float4*)diff;
    #pragma unroll
    for (int i = tid; i < CH * G / 4; i += BT)
        d4[i] = make_float4(0.f, 0.f, 0.f, 0.f);
    __syncthreads();

    #pragma unroll 4
    for (int e = tid; e < E; e += BT) {
        int4 r = rec[e];
        int lo = max(r.x - tb, 0);
        int hi = min(r.y - tb, CH);
        if (lo >= hi) continue;              // no overlap with this slab
        float w = __int_as_float(r.w);
        atomicAdd(diff + lo * G + r.z, w);
        if (hi < CH) atomicAdd(diff + hi * G + r.z, -w);
    }
    __syncthreads();

    // Column prefix-sum: thread tid owns column g=tid. Consecutive lanes hit
    // consecutive banks -> conflict-free.
    {
        float rsum = 0.f;
        #pragma unroll
        for (int t = 0; t < CH; ++t) {
            rsum += diff[t * G + tid];
            diff[t * G + tid] = rsum;
        }
    }
    __syncthreads();

    float4* o4 = (float4*)(out + (size_t)tb * G);
    #pragma unroll
    for (int i = tid; i < CH * G / 4; i += BT)
        o4[i] = d4[i];
}

extern "C" void kernel_launch(void* const* d_in, const int* in_sizes, int n_in,
                              void* d_out, int out_size, void* d_ws, size_t ws_size,
                              hipStream_t stream) {
    const int*   index = (const int*)  d_in[0];
    const float* rate  = (const float*)d_in[1];
    const float* start = (const float*)d_in[2];
    const float* endt  = (const float*)d_in[3];
    const float* t0    = (const float*)d_in[4];
    const int*   gid   = (const int*)  d_in[5];
    const float* wts   = (const float*)d_in[6];
    float* out = (float*)d_out;
    int4* rec = (int4*)d_ws;                 // E * 16 B = 256 KB

    k_prep<<<(E + 255) / 256, 256, 0, stream>>>(index, rate, start, endt, t0, gid, wts, rec);
    k_main<<<NC, BT, 0, stream>>>(rec, out);
}